// Round 20
// baseline (218.955 us; speedup 1.0000x reference)
//
#include <hip/hip_runtime.h>
#include <cstdint>
#include <cstddef>

#define B_ 16
#define E_ 1024
#define N_ 1024
#define H_ 128
#define CAP 192   // max nonzeros per row/col; Binomial(1024,0.1): mean 102, std 9.6 -> 192 = 9.3 sigma
#define NC 32     // e-chunks for column build
#define EC 32     // E_/NC
#define NW 16     // u64 words per 1024-bit row

typedef unsigned short u16;
typedef unsigned long long u64;

#define UPK2(u, flo, fhi) \
    flo = __uint_as_float((u) << 16); fhi = __uint_as_float((u) & 0xffff0000u)

__device__ __forceinline__ u16 f2bf(float f) {   // RTNE float->bf16
    unsigned u = __float_as_uint(f);
    return (u16)((u + 0x7fffu + ((u >> 16) & 1u)) >> 16);
}

__device__ __forceinline__ float wave_sum64(float v) {
    v += __shfl_xor(v, 32);
    v += __shfl_xor(v, 16);
    v += __shfl_xor(v, 8);
    v += __shfl_xor(v, 4);
    v += __shfl_xor(v, 2);
    v += __shfl_xor(v, 1);
    return v;
}

// --- adj (B,E,N) f32 -> bit matrix (B*E rows x 16 u64 words), single pass ---
__global__ void adj_to_bits(const float* __restrict__ adj, u64* __restrict__ bits) {
    int be = blockIdx.x;                      // 16384
    const float* row = adj + (size_t)be * N_;
    int tid = threadIdx.x, lane = tid & 63, wv = tid >> 6;
    for (int c0 = 0; c0 < N_; c0 += 256) {
        float v = row[c0 + tid];
        u64 m = __ballot(v != 0.0f);
        if (lane == 0) bits[(size_t)be * NW + (c0 >> 6) + wv] = m;
    }
}

// --- Row lists from bits: wave per row, 4 rows/block. Ascending n. ---
__global__ void rows_from_bits(const u64* __restrict__ bits,
                               u16* __restrict__ idx, int* __restrict__ cnt_out) {
    int x = blockIdx.x;                       // 4096
    int tid = threadIdx.x, lane = tid & 63, wv = tid >> 6;
    int be = (x << 2) + wv;
    const u64* wds = bits + (size_t)be * NW;
    u64 m = (lane < NW) ? wds[lane] : 0ull;
    int pc = __popcll(m);
    int inc = pc;
#pragma unroll
    for (int o = 1; o < 64; o <<= 1) {
        int t = __shfl_up(inc, o);
        if (lane >= o) inc += t;
    }
    int excl = inc - pc;
    int total = __shfl(inc, 63);
    u16* lst = idx + (size_t)be * CAP;
    int pos = excl;
    u64 mm = m;
    while (mm) {
        int bno = __ffsll(mm) - 1;
        if (pos < CAP) lst[pos] = (u16)((lane << 6) + bno);
        ++pos;
        mm &= mm - 1;
    }
    if (lane == 0) cnt_out[be] = total < CAP ? total : CAP;
}

// --- Column lists from bits, 3-phase (ascending e), broadcast word reads ---
__global__ void col_count_bits(const u64* __restrict__ bits, int* __restrict__ cnt_chunk) {
    int blk = blockIdx.x;                 // B*NC*4 = 2048
    int ng = blk & 3;
    int c  = (blk >> 2) & (NC - 1);
    int b  = blk >> 7;
    int n = (ng << 8) + threadIdx.x;
    const u64* base = bits + ((size_t)(b * E_ + c * EC)) * NW + (n >> 6);
    u64 sel = 1ull << (n & 63);
    int cc = 0;
#pragma unroll 8
    for (int e = 0; e < EC; ++e)
        cc += (base[(size_t)e * NW] & sel) ? 1 : 0;
    cnt_chunk[(size_t)(b * NC + c) * N_ + n] = cc;
}

__global__ void col_prefix(const int* __restrict__ cnt_chunk,
                           int* __restrict__ off_chunk, int* __restrict__ cnt_out) {
    int idx = blockIdx.x * 256 + threadIdx.x;   // b*N + n
    int b = idx >> 10, n = idx & 1023;
    int run = 0;
    for (int c = 0; c < NC; ++c) {
        size_t p = (size_t)(b * NC + c) * N_ + n;
        off_chunk[p] = run;
        run += cnt_chunk[p];
    }
    cnt_out[idx] = run < CAP ? run : CAP;
}

__global__ void col_place_bits(const u64* __restrict__ bits,
                               const int* __restrict__ off_chunk, u16* __restrict__ idx) {
    int blk = blockIdx.x;                 // 2048
    int ng = blk & 3;
    int c  = (blk >> 2) & (NC - 1);
    int b  = blk >> 7;
    int n = (ng << 8) + threadIdx.x;
    const u64* base = bits + ((size_t)(b * E_ + c * EC)) * NW + (n >> 6);
    u64 sel = 1ull << (n & 63);
    int pos = off_chunk[(size_t)(b * NC + c) * N_ + n];
    u16* lst = idx + ((size_t)b * N_ + n) * CAP;
    for (int e = 0; e < EC; ++e) {
        if (base[(size_t)e * NW] & sel) {
            if (pos < CAP) lst[pos] = (u16)(c * EC + e);
            ++pos;
        }
    }
}

// One-time fp32 -> bf16 copy (nodes). 4 elems/thread.
__global__ void to_bf16(const float* __restrict__ in, u16* __restrict__ out) {
    int i = blockIdx.x * 256 + threadIdx.x;     // float4 index
    float4 v = ((const float4*)in)[i];
    ushort4 r;
    r.x = f2bf(v.x); r.y = f2bf(v.y); r.z = f2bf(v.z); r.w = f2bf(v.w);
    ((ushort4*)out)[i] = r;
}

// Wave-per-row edge_init: edge_bf[b,e,:] = bf16(mean of incident node rows).
// 2-deep prefetch (rounds i / i+1 in regs, i+2 in flight).
__global__ void __launch_bounds__(256, 8)
edge_init(const u16* __restrict__ nodes_bf,
          const u16* __restrict__ ridx, const int* __restrict__ rcnt,
          u16* __restrict__ edge_bf_out) {
    int x = blockIdx.x;                  // B_*E_/4 = 4096
    int xcd = x & 7;
    int j = x >> 3;                      // 0..511
    int b = xcd + ((j >> 8) << 3);       // batches {xcd, xcd+8}
    int rg = (j & 255) << 2;
    int tid = threadIdx.x, lane = tid & 63, wv = tid >> 6;
    int be = (b << 10) + rg + wv;        // this wave's edge row
    __shared__ u16 sidx[4][CAP];
    int cnt = rcnt[be];
    for (int i = lane; i < cnt; i += 64) sidx[wv][i] = ridx[(size_t)be * CAP + i];

    int esub = lane >> 3, dsub = lane & 7;
    const uint4* kb4 = (const uint4*)(nodes_bf + (size_t)b * N_ * H_);
    float4 a0 = make_float4(0.f, 0.f, 0.f, 0.f);
    float4 a1 = a0, a2 = a0, a3 = a0;

    unsigned r0 = (unsigned)((esub < cnt) ? sidx[wv][esub] : 0) * 16 + (dsub << 1);
    uint4 g0 = kb4[r0], g1 = kb4[r0 + 1];
    int i1 = 8 + esub;
    unsigned r1 = (unsigned)((i1 < cnt) ? sidx[wv][i1] : 0) * 16 + (dsub << 1);
    uint4 h0 = kb4[r1], h1 = kb4[r1 + 1];

    for (int i0 = 0; i0 < cnt; i0 += 8) {
        int inx = i0 + 16 + esub;
        unsigned rn = (unsigned)((inx < cnt) ? sidx[wv][inx] : 0) * 16 + (dsub << 1);
        uint4 n0 = kb4[rn];
        uint4 n1 = kb4[rn + 1];
        int i = i0 + esub;
        float f0, f1, f2, f3, f4, f5, f6, f7;
        float f8, f9, f10, f11, f12, f13, f14, f15;
        UPK2(g0.x, f0, f1);   UPK2(g0.y, f2, f3);
        UPK2(g0.z, f4, f5);   UPK2(g0.w, f6, f7);
        UPK2(g1.x, f8, f9);   UPK2(g1.y, f10, f11);
        UPK2(g1.z, f12, f13); UPK2(g1.w, f14, f15);
        float ww = (i < cnt) ? 1.0f : 0.f;
        a0.x = fmaf(ww, f0, a0.x);  a0.y = fmaf(ww, f1, a0.y);
        a0.z = fmaf(ww, f2, a0.z);  a0.w = fmaf(ww, f3, a0.w);
        a1.x = fmaf(ww, f4, a1.x);  a1.y = fmaf(ww, f5, a1.y);
        a1.z = fmaf(ww, f6, a1.z);  a1.w = fmaf(ww, f7, a1.w);
        a2.x = fmaf(ww, f8, a2.x);  a2.y = fmaf(ww, f9, a2.y);
        a2.z = fmaf(ww, f10, a2.z); a2.w = fmaf(ww, f11, a2.w);
        a3.x = fmaf(ww, f12, a3.x); a3.y = fmaf(ww, f13, a3.y);
        a3.z = fmaf(ww, f14, a3.z); a3.w = fmaf(ww, f15, a3.w);
        g0 = h0; g1 = h1; h0 = n0; h1 = n1;
    }

#define RED3(f) f += __shfl_xor(f, 8); f += __shfl_xor(f, 16); f += __shfl_xor(f, 32)
    RED3(a0.x); RED3(a0.y); RED3(a0.z); RED3(a0.w);
    RED3(a1.x); RED3(a1.y); RED3(a1.z); RED3(a1.w);
    RED3(a2.x); RED3(a2.y); RED3(a2.z); RED3(a2.w);
    RED3(a3.x); RED3(a3.y); RED3(a3.z); RED3(a3.w);
#undef RED3
    if (esub == 0) {
        float inv = 1.0f / (float)(cnt > 0 ? cnt : 1);
        ushort4 h0o, h1o, h2o, h3o;
        h0o.x = f2bf(a0.x * inv); h0o.y = f2bf(a0.y * inv);
        h0o.z = f2bf(a0.z * inv); h0o.w = f2bf(a0.w * inv);
        h1o.x = f2bf(a1.x * inv); h1o.y = f2bf(a1.y * inv);
        h1o.z = f2bf(a1.z * inv); h1o.w = f2bf(a1.w * inv);
        h2o.x = f2bf(a2.x * inv); h2o.y = f2bf(a2.y * inv);
        h2o.z = f2bf(a2.z * inv); h2o.w = f2bf(a2.w * inv);
        h3o.x = f2bf(a3.x * inv); h3o.y = f2bf(a3.y * inv);
        h3o.z = f2bf(a3.z * inv); h3o.w = f2bf(a3.w * inv);
        ushort4* hp = (ushort4*)edge_bf_out + (size_t)be * 32 + (dsub << 2);
        hp[0] = h0o; hp[1] = h1o; hp[2] = h2o; hp[3] = h3o;
    }
}

// Wave-per-row fused masked-softmax attention, bf16 KV gather, bf16 q source,
// 2-DEEP prefetch (rounds i in compute, i+1 in regs, i+2 loads in flight):
// covers ~260 cyc > L2 ~200 cyc (1-deep gave only ~130 cyc -> 40% stall).
// wfp=0 skips fp32 output; wbf=0 skips bf16 shadow. Row-local alias safe.
// XCD swizzle: batch b on XCD b%8 -> per-XCD kv footprint L2-resident.
__global__ void __launch_bounds__(256, 4)
attn_gather(const u16* __restrict__ q_bf,
            const u16* __restrict__ kv_bf,
            const float* __restrict__ w,
            const u16* __restrict__ lidx, const int* __restrict__ lcnt,
            float* __restrict__ out, u16* __restrict__ out_bf, int wbf, int wfp) {
    int x = blockIdx.x;                  // 4096 blocks
    int xcd = x & 7;
    int j = x >> 3;                      // 0..511
    int b = xcd + ((j >> 8) << 3);       // batches {xcd, xcd+8}
    int rg = (j & 255) << 2;             // 4-row group
    int tid = threadIdx.x, lane = tid & 63, wv = tid >> 6;
    int br = (b << 10) + rg + wv;        // this wave's row
    __shared__ u16 sidx[4][CAP];
    int cnt = lcnt[br];
    for (int i = lane; i < cnt; i += 64) sidx[wv][i] = lidx[(size_t)br * CAP + i];

    int esub = lane >> 3, dsub = lane & 7;   // entry-in-round, d-slice
    // q (bf16) -> registers, * w * log2e  (dims [16*dsub, 16*dsub+16))
    const uint4* qp4 = (const uint4*)(q_bf + (size_t)br * H_);
    uint4 qg0 = qp4[(dsub << 1)];
    uint4 qg1 = qp4[(dsub << 1) + 1];
    const float4* wp = (const float4*)w;
    float4 qr0, qr1, qr2, qr3;
    {
        const float L2E = 1.44269504f;
        float u0, u1, u2, u3, u4, u5, u6, u7;
        float u8, u9, u10, u11, u12, u13, u14, u15;
        UPK2(qg0.x, u0, u1);   UPK2(qg0.y, u2, u3);
        UPK2(qg0.z, u4, u5);   UPK2(qg0.w, u6, u7);
        UPK2(qg1.x, u8, u9);   UPK2(qg1.y, u10, u11);
        UPK2(qg1.z, u12, u13); UPK2(qg1.w, u14, u15);
        float4 w0 = wp[(dsub << 2) + 0], w1 = wp[(dsub << 2) + 1];
        float4 w2 = wp[(dsub << 2) + 2], w3 = wp[(dsub << 2) + 3];
        qr0.x = u0 * w0.x * L2E;  qr0.y = u1 * w0.y * L2E;
        qr0.z = u2 * w0.z * L2E;  qr0.w = u3 * w0.w * L2E;
        qr1.x = u4 * w1.x * L2E;  qr1.y = u5 * w1.y * L2E;
        qr1.z = u6 * w1.z * L2E;  qr1.w = u7 * w1.w * L2E;
        qr2.x = u8 * w2.x * L2E;  qr2.y = u9 * w2.y * L2E;
        qr2.z = u10 * w2.z * L2E; qr2.w = u11 * w2.w * L2E;
        qr3.x = u12 * w3.x * L2E; qr3.y = u13 * w3.y * L2E;
        qr3.z = u14 * w3.z * L2E; qr3.w = u15 * w3.w * L2E;
    }
    float wb = w[H_] * 1.44269504f;
    const uint4* kb4 = (const uint4*)(kv_bf + (size_t)b * 1024 * H_);

    float4 a0 = make_float4(0.f, 0.f, 0.f, 0.f);
    float4 a1 = a0, a2 = a0, a3 = a0;
    float dpart = 0.f;

    // prime rounds 0 and 1
    unsigned r0i = (unsigned)((esub < cnt) ? sidx[wv][esub] : 0) * 16 + (dsub << 1);
    uint4 g0 = kb4[r0i], g1 = kb4[r0i + 1];
    int i1 = 8 + esub;
    unsigned r1i = (unsigned)((i1 < cnt) ? sidx[wv][i1] : 0) * 16 + (dsub << 1);
    uint4 h0 = kb4[r1i], h1 = kb4[r1i + 1];

    for (int i0 = 0; i0 < cnt; i0 += 8) {
        int inx = i0 + 16 + esub;
        unsigned rn = (unsigned)((inx < cnt) ? sidx[wv][inx] : 0) * 16 + (dsub << 1);
        uint4 n0 = kb4[rn];
        uint4 n1 = kb4[rn + 1];
        int i = i0 + esub;
        float f0, f1, f2, f3, f4, f5, f6, f7;
        float f8, f9, f10, f11, f12, f13, f14, f15;
        UPK2(g0.x, f0, f1);   UPK2(g0.y, f2, f3);
        UPK2(g0.z, f4, f5);   UPK2(g0.w, f6, f7);
        UPK2(g1.x, f8, f9);   UPK2(g1.y, f10, f11);
        UPK2(g1.z, f12, f13); UPK2(g1.w, f14, f15);
        float dA = 0.f, dB = 0.f;
        dA = fmaf(f0, qr0.x, dA);  dB = fmaf(f1, qr0.y, dB);
        dA = fmaf(f2, qr0.z, dA);  dB = fmaf(f3, qr0.w, dB);
        dA = fmaf(f4, qr1.x, dA);  dB = fmaf(f5, qr1.y, dB);
        dA = fmaf(f6, qr1.z, dA);  dB = fmaf(f7, qr1.w, dB);
        dA = fmaf(f8, qr2.x, dA);  dB = fmaf(f9, qr2.y, dB);
        dA = fmaf(f10, qr2.z, dA); dB = fmaf(f11, qr2.w, dB);
        dA = fmaf(f12, qr3.x, dA); dB = fmaf(f13, qr3.y, dB);
        dA = fmaf(f14, qr3.z, dA); dB = fmaf(f15, qr3.w, dB);
        float d = dA + dB;
        d += __shfl_xor(d, 1);
        d += __shfl_xor(d, 2);
        d += __shfl_xor(d, 4);           // all 8 lanes of entry hold full dot
        float p = d + wb;
        p = p >= 0.f ? p : 0.2f * p;     // LeakyReLU(0.2), commutes with log2e scale
        float ww = (i < cnt) ? exp2f(p) : 0.f;
        dpart += ww;
        a0.x = fmaf(ww, f0, a0.x);  a0.y = fmaf(ww, f1, a0.y);
        a0.z = fmaf(ww, f2, a0.z);  a0.w = fmaf(ww, f3, a0.w);
        a1.x = fmaf(ww, f4, a1.x);  a1.y = fmaf(ww, f5, a1.y);
        a1.z = fmaf(ww, f6, a1.z);  a1.w = fmaf(ww, f7, a1.w);
        a2.x = fmaf(ww, f8, a2.x);  a2.y = fmaf(ww, f9, a2.y);
        a2.z = fmaf(ww, f10, a2.z); a2.w = fmaf(ww, f11, a2.w);
        a3.x = fmaf(ww, f12, a3.x); a3.y = fmaf(ww, f13, a3.y);
        a3.z = fmaf(ww, f14, a3.z); a3.w = fmaf(ww, f15, a3.w);
        g0 = h0; g1 = h1; h0 = n0; h1 = n1;
    }

    // intra-wave merge across esub groups (xor 8/16/32); all lanes end full.
#define RED3(f) f += __shfl_xor(f, 8); f += __shfl_xor(f, 16); f += __shfl_xor(f, 32)
    RED3(a0.x); RED3(a0.y); RED3(a0.z); RED3(a0.w);
    RED3(a1.x); RED3(a1.y); RED3(a1.z); RED3(a1.w);
    RED3(a2.x); RED3(a2.y); RED3(a2.z); RED3(a2.w);
    RED3(a3.x); RED3(a3.y); RED3(a3.z); RED3(a3.w);
#undef RED3
    float denom = wave_sum64(dpart) * 0.125f;   // each entry counted by 8 lanes
    float rden = denom > 0.f ? 1.0f / denom : 0.f;

    if (esub == 0) {                      // lanes 0..7, lane == dsub
        a0.x *= rden; a0.y *= rden; a0.z *= rden; a0.w *= rden;
        a1.x *= rden; a1.y *= rden; a1.z *= rden; a1.w *= rden;
        a2.x *= rden; a2.y *= rden; a2.z *= rden; a2.w *= rden;
        a3.x *= rden; a3.y *= rden; a3.z *= rden; a3.w *= rden;
        if (wfp) {
            float4* op = (float4*)out + (size_t)br * 32 + (dsub << 2);
            op[0] = a0; op[1] = a1; op[2] = a2; op[3] = a3;
        }
        if (wbf) {
            ushort4* hp = (ushort4*)out_bf + (size_t)br * 32 + (dsub << 2);
            ushort4 h0o, h1o, h2o, h3o;
            h0o.x = f2bf(a0.x); h0o.y = f2bf(a0.y); h0o.z = f2bf(a0.z); h0o.w = f2bf(a0.w);
            h1o.x = f2bf(a1.x); h1o.y = f2bf(a1.y); h1o.z = f2bf(a1.z); h1o.w = f2bf(a1.w);
            h2o.x = f2bf(a2.x); h2o.y = f2bf(a2.y); h2o.z = f2bf(a2.z); h2o.w = f2bf(a2.w);
            h3o.x = f2bf(a3.x); h3o.y = f2bf(a3.y); h3o.z = f2bf(a3.z); h3o.w = f2bf(a3.w);
            hp[0] = h0o; hp[1] = h1o; hp[2] = h2o; hp[3] = h3o;
        }
    }
}

extern "C" void kernel_launch(void* const* d_in, const int* in_sizes, int n_in,
                              void* d_out, int out_size, void* d_ws, size_t ws_size,
                              hipStream_t stream) {
    const float* nodes_in = (const float*)d_in[0];   // (B,N,H) f32
    const float* adj      = (const float*)d_in[1];   // (B,E,N) f32, binary
    const float* w1       = (const float*)d_in[2];   // (H+1)
    const float* w2       = (const float*)d_in[3];   // (H+1)

    char* ws = (char*)d_ws;
    size_t off = 0;
    u16* row_idx = (u16*)(ws + off); off += (size_t)B_ * E_ * CAP * sizeof(u16);
    u16* col_idx = (u16*)(ws + off); off += (size_t)B_ * N_ * CAP * sizeof(u16);
    int* row_cnt = (int*)(ws + off); off += (size_t)B_ * E_ * sizeof(int);
    int* col_cnt = (int*)(ws + off); off += (size_t)B_ * N_ * sizeof(int);
    int* cnt_chunk = (int*)(ws + off); off += (size_t)B_ * NC * N_ * sizeof(int);
    int* off_chunk = (int*)(ws + off); off += (size_t)B_ * NC * N_ * sizeof(int);
    u16* nodes_bf = (u16*)(ws + off); off += (size_t)B_ * N_ * H_ * sizeof(u16);
    u16* edge_bf  = (u16*)(ws + off); off += (size_t)B_ * E_ * H_ * sizeof(u16);
    u64* bits     = (u64*)(ws + off); off += (size_t)B_ * E_ * NW * sizeof(u64);

    float* out_nodes = (float*)d_out;                       // (B,N,H)
    float* out_edge  = out_nodes + (size_t)B_ * N_ * H_;    // (B,E,H)

    adj_to_bits   <<<dim3(B_ * E_), dim3(256), 0, stream>>>(adj, bits);
    rows_from_bits<<<dim3(B_ * E_ / 4), dim3(256), 0, stream>>>(bits, row_idx, row_cnt);
    col_count_bits<<<dim3(B_ * NC * 4), dim3(256), 0, stream>>>(bits, cnt_chunk);
    col_prefix    <<<dim3(B_ * N_ / 256), dim3(256), 0, stream>>>(cnt_chunk, off_chunk, col_cnt);
    col_place_bits<<<dim3(B_ * NC * 4), dim3(256), 0, stream>>>(bits, off_chunk, col_idx);
    to_bf16       <<<dim3(B_ * N_ * H_ / 1024), dim3(256), 0, stream>>>(nodes_in, nodes_bf);
    edge_init     <<<dim3(B_ * E_ / 4), dim3(256), 0, stream>>>(nodes_bf, row_idx, row_cnt, edge_bf);

    // s=0: intermediates -> bf16 shadows only (wfp=0)
    attn_gather<<<dim3(B_ * E_ / 4), dim3(256), 0, stream>>>(
        edge_bf, nodes_bf, w1, row_idx, row_cnt, out_edge, edge_bf, 1, 0);
    attn_gather<<<dim3(B_ * N_ / 4), dim3(256), 0, stream>>>(
        nodes_bf, edge_bf, w2, col_idx, col_cnt, out_nodes, nodes_bf, 1, 0);
    // s=1: finals -> fp32 outputs (wfp=1); edge also keeps bf16 for beta's kv
    attn_gather<<<dim3(B_ * E_ / 4), dim3(256), 0, stream>>>(
        edge_bf, nodes_bf, w1, row_idx, row_cnt, out_edge, edge_bf, 1, 1);
    attn_gather<<<dim3(B_ * N_ / 4), dim3(256), 0, stream>>>(
        nodes_bf, edge_bf, w2, col_idx, col_cnt, out_nodes, nodes_bf, 0, 1);
}

// Round 24
// 215.839 us; speedup vs baseline: 1.0144x; 1.0144x over previous
//
#include <hip/hip_runtime.h>
#include <cstdint>
#include <cstddef>

#define B_ 16
#define E_ 1024
#define N_ 1024
#define H_ 128
#define CAP 192   // max nonzeros per row/col; Binomial(1024,0.1): mean 102, std 9.6 -> 192 = 9.3 sigma
#define NC 32     // e-chunks for column build
#define EC 32     // E_/NC
#define NW 16     // u64 words per 1024-bit row

typedef unsigned short u16;
typedef unsigned long long u64;

#define UPK2(u, flo, fhi) \
    flo = __uint_as_float((u) << 16); fhi = __uint_as_float((u) & 0xffff0000u)

__device__ __forceinline__ u16 f2bf(float f) {   // RTNE float->bf16
    unsigned u = __float_as_uint(f);
    return (u16)((u + 0x7fffu + ((u >> 16) & 1u)) >> 16);
}

__device__ __forceinline__ float wave_sum64(float v) {
    v += __shfl_xor(v, 32);
    v += __shfl_xor(v, 16);
    v += __shfl_xor(v, 8);
    v += __shfl_xor(v, 4);
    v += __shfl_xor(v, 2);
    v += __shfl_xor(v, 1);
    return v;
}

// --- adj (B,E,N) f32 -> bit matrix (B*E rows x 16 u64 words), single pass ---
__global__ void adj_to_bits(const float* __restrict__ adj, u64* __restrict__ bits) {
    int be = blockIdx.x;                      // 16384
    const float* row = adj + (size_t)be * N_;
    int tid = threadIdx.x, lane = tid & 63, wv = tid >> 6;
    for (int c0 = 0; c0 < N_; c0 += 256) {
        float v = row[c0 + tid];
        u64 m = __ballot(v != 0.0f);
        if (lane == 0) bits[(size_t)be * NW + (c0 >> 6) + wv] = m;
    }
}

// --- Row lists from bits: wave per row, 4 rows/block. Ascending n. ---
__global__ void rows_from_bits(const u64* __restrict__ bits,
                               u16* __restrict__ idx, int* __restrict__ cnt_out) {
    int x = blockIdx.x;                       // 4096
    int tid = threadIdx.x, lane = tid & 63, wv = tid >> 6;
    int be = (x << 2) + wv;
    const u64* wds = bits + (size_t)be * NW;
    u64 m = (lane < NW) ? wds[lane] : 0ull;
    int pc = __popcll(m);
    int inc = pc;
#pragma unroll
    for (int o = 1; o < 64; o <<= 1) {
        int t = __shfl_up(inc, o);
        if (lane >= o) inc += t;
    }
    int excl = inc - pc;
    int total = __shfl(inc, 63);
    u16* lst = idx + (size_t)be * CAP;
    int pos = excl;
    u64 mm = m;
    while (mm) {
        int bno = __ffsll(mm) - 1;
        if (pos < CAP) lst[pos] = (u16)((lane << 6) + bno);
        ++pos;
        mm &= mm - 1;
    }
    if (lane == 0) cnt_out[be] = total < CAP ? total : CAP;
}

// --- Column lists from bits, 3-phase (ascending e), broadcast word reads ---
__global__ void col_count_bits(const u64* __restrict__ bits, int* __restrict__ cnt_chunk) {
    int blk = blockIdx.x;                 // B*NC*4 = 2048
    int ng = blk & 3;
    int c  = (blk >> 2) & (NC - 1);
    int b  = blk >> 7;
    int n = (ng << 8) + threadIdx.x;
    const u64* base = bits + ((size_t)(b * E_ + c * EC)) * NW + (n >> 6);
    u64 sel = 1ull << (n & 63);
    int cc = 0;
#pragma unroll 8
    for (int e = 0; e < EC; ++e)
        cc += (base[(size_t)e * NW] & sel) ? 1 : 0;
    cnt_chunk[(size_t)(b * NC + c) * N_ + n] = cc;
}

__global__ void col_prefix(const int* __restrict__ cnt_chunk,
                           int* __restrict__ off_chunk, int* __restrict__ cnt_out) {
    int idx = blockIdx.x * 256 + threadIdx.x;   // b*N + n
    int b = idx >> 10, n = idx & 1023;
    int run = 0;
    for (int c = 0; c < NC; ++c) {
        size_t p = (size_t)(b * NC + c) * N_ + n;
        off_chunk[p] = run;
        run += cnt_chunk[p];
    }
    cnt_out[idx] = run < CAP ? run : CAP;
}

__global__ void col_place_bits(const u64* __restrict__ bits,
                               const int* __restrict__ off_chunk, u16* __restrict__ idx) {
    int blk = blockIdx.x;                 // 2048
    int ng = blk & 3;
    int c  = (blk >> 2) & (NC - 1);
    int b  = blk >> 7;
    int n = (ng << 8) + threadIdx.x;
    const u64* base = bits + ((size_t)(b * E_ + c * EC)) * NW + (n >> 6);
    u64 sel = 1ull << (n & 63);
    int pos = off_chunk[(size_t)(b * NC + c) * N_ + n];
    u16* lst = idx + ((size_t)b * N_ + n) * CAP;
    for (int e = 0; e < EC; ++e) {
        if (base[(size_t)e * NW] & sel) {
            if (pos < CAP) lst[pos] = (u16)(c * EC + e);
            ++pos;
        }
    }
}

// One-time fp32 -> bf16 copy (nodes). 4 elems/thread.
__global__ void to_bf16(const float* __restrict__ in, u16* __restrict__ out) {
    int i = blockIdx.x * 256 + threadIdx.x;     // float4 index
    float4 v = ((const float4*)in)[i];
    ushort4 r;
    r.x = f2bf(v.x); r.y = f2bf(v.y); r.z = f2bf(v.z); r.w = f2bf(v.w);
    ((ushort4*)out)[i] = r;
}

// Wave-per-row edge_init: edge_bf[b,e,:] = bf16(mean of incident node rows).
// (bf16 output only — alpha s=0 reads bf16 q; fp32 edge comes from alpha s=1.)
__global__ void __launch_bounds__(256, 8)
edge_init(const u16* __restrict__ nodes_bf,
          const u16* __restrict__ ridx, const int* __restrict__ rcnt,
          u16* __restrict__ edge_bf_out) {
    int x = blockIdx.x;                  // B_*E_/4 = 4096
    int xcd = x & 7;
    int j = x >> 3;                      // 0..511
    int b = xcd + ((j >> 8) << 3);       // batches {xcd, xcd+8}
    int rg = (j & 255) << 2;
    int tid = threadIdx.x, lane = tid & 63, wv = tid >> 6;
    int be = (b << 10) + rg + wv;        // this wave's edge row
    __shared__ u16 sidx[4][CAP];
    int cnt = rcnt[be];
    for (int i = lane; i < cnt; i += 64) sidx[wv][i] = ridx[(size_t)be * CAP + i];

    int esub = lane >> 3, dsub = lane & 7;
    const uint4* kb4 = (const uint4*)(nodes_bf + (size_t)b * N_ * H_);
    float4 a0 = make_float4(0.f, 0.f, 0.f, 0.f);
    float4 a1 = a0, a2 = a0, a3 = a0;

    unsigned ro = (unsigned)((esub < cnt) ? sidx[wv][esub] : 0) * 16 + (dsub << 1);
    uint4 g0 = kb4[ro];
    uint4 g1 = kb4[ro + 1];

    for (int i0 = 0; i0 < cnt; i0 += 8) {
        int inx = i0 + 8 + esub;
        unsigned rn = (unsigned)((inx < cnt) ? sidx[wv][inx] : 0) * 16 + (dsub << 1);
        uint4 n0 = kb4[rn];
        uint4 n1 = kb4[rn + 1];
        int i = i0 + esub;
        float f0, f1, f2, f3, f4, f5, f6, f7;
        float f8, f9, f10, f11, f12, f13, f14, f15;
        UPK2(g0.x, f0, f1);   UPK2(g0.y, f2, f3);
        UPK2(g0.z, f4, f5);   UPK2(g0.w, f6, f7);
        UPK2(g1.x, f8, f9);   UPK2(g1.y, f10, f11);
        UPK2(g1.z, f12, f13); UPK2(g1.w, f14, f15);
        float ww = (i < cnt) ? 1.0f : 0.f;
        a0.x = fmaf(ww, f0, a0.x);  a0.y = fmaf(ww, f1, a0.y);
        a0.z = fmaf(ww, f2, a0.z);  a0.w = fmaf(ww, f3, a0.w);
        a1.x = fmaf(ww, f4, a1.x);  a1.y = fmaf(ww, f5, a1.y);
        a1.z = fmaf(ww, f6, a1.z);  a1.w = fmaf(ww, f7, a1.w);
        a2.x = fmaf(ww, f8, a2.x);  a2.y = fmaf(ww, f9, a2.y);
        a2.z = fmaf(ww, f10, a2.z); a2.w = fmaf(ww, f11, a2.w);
        a3.x = fmaf(ww, f12, a3.x); a3.y = fmaf(ww, f13, a3.y);
        a3.z = fmaf(ww, f14, a3.z); a3.w = fmaf(ww, f15, a3.w);
        g0 = n0; g1 = n1;
    }

#define RED3(f) f += __shfl_xor(f, 8); f += __shfl_xor(f, 16); f += __shfl_xor(f, 32)
    RED3(a0.x); RED3(a0.y); RED3(a0.z); RED3(a0.w);
    RED3(a1.x); RED3(a1.y); RED3(a1.z); RED3(a1.w);
    RED3(a2.x); RED3(a2.y); RED3(a2.z); RED3(a2.w);
    RED3(a3.x); RED3(a3.y); RED3(a3.z); RED3(a3.w);
#undef RED3
    if (esub == 0) {
        float inv = 1.0f / (float)(cnt > 0 ? cnt : 1);
        ushort4 h0, h1, h2, h3;
        h0.x = f2bf(a0.x * inv); h0.y = f2bf(a0.y * inv);
        h0.z = f2bf(a0.z * inv); h0.w = f2bf(a0.w * inv);
        h1.x = f2bf(a1.x * inv); h1.y = f2bf(a1.y * inv);
        h1.z = f2bf(a1.z * inv); h1.w = f2bf(a1.w * inv);
        h2.x = f2bf(a2.x * inv); h2.y = f2bf(a2.y * inv);
        h2.z = f2bf(a2.z * inv); h2.w = f2bf(a2.w * inv);
        h3.x = f2bf(a3.x * inv); h3.y = f2bf(a3.y * inv);
        h3.z = f2bf(a3.z * inv); h3.w = f2bf(a3.w * inv);
        ushort4* hp = (ushort4*)edge_bf_out + (size_t)be * 32 + (dsub << 2);
        hp[0] = h0; hp[1] = h1; hp[2] = h2; hp[3] = h3;
    }
}

// Wave-per-row fused masked-softmax attention, bf16 KV gather, bf16 q source
// (q*w product kept in fp32 — 16-bit pre-rounding of q*w failed numerics in
// r21/r23; plain fmaf beat pk_fma (r18) and dot2 (r21/r23); 1-deep prefetch
// beat 2-deep (r20)). This is the measured optimum structure.
// wfp=0 skips the fp32 output write (intermediate dispatches); wbf=0 skips
// the bf16 shadow write (final beta). Row-local aliasing q_bf==out_bf safe.
// XCD swizzle: batch b on XCD b%8 -> per-XCD kv footprint L2-resident.
__global__ void __launch_bounds__(256, 4)
attn_gather(const u16* __restrict__ q_bf,
            const u16* __restrict__ kv_bf,
            const float* __restrict__ w,
            const u16* __restrict__ lidx, const int* __restrict__ lcnt,
            float* __restrict__ out, u16* __restrict__ out_bf, int wbf, int wfp) {
    int x = blockIdx.x;                  // 4096 blocks
    int xcd = x & 7;
    int j = x >> 3;                      // 0..511
    int b = xcd + ((j >> 8) << 3);       // batches {xcd, xcd+8}
    int rg = (j & 255) << 2;             // 4-row group
    int tid = threadIdx.x, lane = tid & 63, wv = tid >> 6;
    int br = (b << 10) + rg + wv;        // this wave's row
    __shared__ u16 sidx[4][CAP];
    int cnt = lcnt[br];
    for (int i = lane; i < cnt; i += 64) sidx[wv][i] = lidx[(size_t)br * CAP + i];

    int esub = lane >> 3, dsub = lane & 7;   // entry-in-round, d-slice
    // q (bf16) -> registers, * w * log2e in fp32 (dims [16*dsub, 16*dsub+16))
    const uint4* qp4 = (const uint4*)(q_bf + (size_t)br * H_);
    uint4 qg0 = qp4[(dsub << 1)];
    uint4 qg1 = qp4[(dsub << 1) + 1];
    const float4* wp = (const float4*)w;
    float4 qr0, qr1, qr2, qr3;
    {
        const float L2E = 1.44269504f;
        float u0, u1, u2, u3, u4, u5, u6, u7;
        float u8, u9, u10, u11, u12, u13, u14, u15;
        UPK2(qg0.x, u0, u1);   UPK2(qg0.y, u2, u3);
        UPK2(qg0.z, u4, u5);   UPK2(qg0.w, u6, u7);
        UPK2(qg1.x, u8, u9);   UPK2(qg1.y, u10, u11);
        UPK2(qg1.z, u12, u13); UPK2(qg1.w, u14, u15);
        float4 w0 = wp[(dsub << 2) + 0], w1 = wp[(dsub << 2) + 1];
        float4 w2 = wp[(dsub << 2) + 2], w3 = wp[(dsub << 2) + 3];
        qr0.x = u0 * w0.x * L2E;  qr0.y = u1 * w0.y * L2E;
        qr0.z = u2 * w0.z * L2E;  qr0.w = u3 * w0.w * L2E;
        qr1.x = u4 * w1.x * L2E;  qr1.y = u5 * w1.y * L2E;
        qr1.z = u6 * w1.z * L2E;  qr1.w = u7 * w1.w * L2E;
        qr2.x = u8 * w2.x * L2E;  qr2.y = u9 * w2.y * L2E;
        qr2.z = u10 * w2.z * L2E; qr2.w = u11 * w2.w * L2E;
        qr3.x = u12 * w3.x * L2E; qr3.y = u13 * w3.y * L2E;
        qr3.z = u14 * w3.z * L2E; qr3.w = u15 * w3.w * L2E;
    }
    float wb = w[H_] * 1.44269504f;
    const uint4* kb4 = (const uint4*)(kv_bf + (size_t)b * 1024 * H_);

    float4 a0 = make_float4(0.f, 0.f, 0.f, 0.f);
    float4 a1 = a0, a2 = a0, a3 = a0;
    float dpart = 0.f;

    unsigned ro = (unsigned)((esub < cnt) ? sidx[wv][esub] : 0) * 16 + (dsub << 1);
    uint4 g0 = kb4[ro];
    uint4 g1 = kb4[ro + 1];

    for (int i0 = 0; i0 < cnt; i0 += 8) {
        int inx = i0 + 8 + esub;
        unsigned rn = (unsigned)((inx < cnt) ? sidx[wv][inx] : 0) * 16 + (dsub << 1);
        uint4 n0 = kb4[rn];
        uint4 n1 = kb4[rn + 1];
        int i = i0 + esub;
        float f0, f1, f2, f3, f4, f5, f6, f7;
        float f8, f9, f10, f11, f12, f13, f14, f15;
        UPK2(g0.x, f0, f1);   UPK2(g0.y, f2, f3);
        UPK2(g0.z, f4, f5);   UPK2(g0.w, f6, f7);
        UPK2(g1.x, f8, f9);   UPK2(g1.y, f10, f11);
        UPK2(g1.z, f12, f13); UPK2(g1.w, f14, f15);
        float dA = 0.f, dB = 0.f;
        dA = fmaf(f0, qr0.x, dA);  dB = fmaf(f1, qr0.y, dB);
        dA = fmaf(f2, qr0.z, dA);  dB = fmaf(f3, qr0.w, dB);
        dA = fmaf(f4, qr1.x, dA);  dB = fmaf(f5, qr1.y, dB);
        dA = fmaf(f6, qr1.z, dA);  dB = fmaf(f7, qr1.w, dB);
        dA = fmaf(f8, qr2.x, dA);  dB = fmaf(f9, qr2.y, dB);
        dA = fmaf(f10, qr2.z, dA); dB = fmaf(f11, qr2.w, dB);
        dA = fmaf(f12, qr3.x, dA); dB = fmaf(f13, qr3.y, dB);
        dA = fmaf(f14, qr3.z, dA); dB = fmaf(f15, qr3.w, dB);
        float d = dA + dB;
        d += __shfl_xor(d, 1);
        d += __shfl_xor(d, 2);
        d += __shfl_xor(d, 4);           // all 8 lanes of entry hold full dot
        float p = d + wb;
        p = p >= 0.f ? p : 0.2f * p;     // LeakyReLU(0.2), commutes with log2e scale
        float ww = (i < cnt) ? exp2f(p) : 0.f;
        dpart += ww;
        a0.x = fmaf(ww, f0, a0.x);  a0.y = fmaf(ww, f1, a0.y);
        a0.z = fmaf(ww, f2, a0.z);  a0.w = fmaf(ww, f3, a0.w);
        a1.x = fmaf(ww, f4, a1.x);  a1.y = fmaf(ww, f5, a1.y);
        a1.z = fmaf(ww, f6, a1.z);  a1.w = fmaf(ww, f7, a1.w);
        a2.x = fmaf(ww, f8, a2.x);  a2.y = fmaf(ww, f9, a2.y);
        a2.z = fmaf(ww, f10, a2.z); a2.w = fmaf(ww, f11, a2.w);
        a3.x = fmaf(ww, f12, a3.x); a3.y = fmaf(ww, f13, a3.y);
        a3.z = fmaf(ww, f14, a3.z); a3.w = fmaf(ww, f15, a3.w);
        g0 = n0; g1 = n1;
    }

    // intra-wave merge across esub groups (xor 8/16/32); all lanes end full.
#define RED3(f) f += __shfl_xor(f, 8); f += __shfl_xor(f, 16); f += __shfl_xor(f, 32)
    RED3(a0.x); RED3(a0.y); RED3(a0.z); RED3(a0.w);
    RED3(a1.x); RED3(a1.y); RED3(a1.z); RED3(a1.w);
    RED3(a2.x); RED3(a2.y); RED3(a2.z); RED3(a2.w);
    RED3(a3.x); RED3(a3.y); RED3(a3.z); RED3(a3.w);
#undef RED3
    float denom = wave_sum64(dpart) * 0.125f;   // each entry counted by 8 lanes
    float rden = denom > 0.f ? 1.0f / denom : 0.f;

    if (esub == 0) {                      // lanes 0..7, lane == dsub
        a0.x *= rden; a0.y *= rden; a0.z *= rden; a0.w *= rden;
        a1.x *= rden; a1.y *= rden; a1.z *= rden; a1.w *= rden;
        a2.x *= rden; a2.y *= rden; a2.z *= rden; a2.w *= rden;
        a3.x *= rden; a3.y *= rden; a3.z *= rden; a3.w *= rden;
        if (wfp) {
            float4* op = (float4*)out + (size_t)br * 32 + (dsub << 2);
            op[0] = a0; op[1] = a1; op[2] = a2; op[3] = a3;
        }
        if (wbf) {
            ushort4* hp = (ushort4*)out_bf + (size_t)br * 32 + (dsub << 2);
            ushort4 h0o, h1o, h2o, h3o;
            h0o.x = f2bf(a0.x); h0o.y = f2bf(a0.y); h0o.z = f2bf(a0.z); h0o.w = f2bf(a0.w);
            h1o.x = f2bf(a1.x); h1o.y = f2bf(a1.y); h1o.z = f2bf(a1.z); h1o.w = f2bf(a1.w);
            h2o.x = f2bf(a2.x); h2o.y = f2bf(a2.y); h2o.z = f2bf(a2.z); h2o.w = f2bf(a2.w);
            h3o.x = f2bf(a3.x); h3o.y = f2bf(a3.y); h3o.z = f2bf(a3.z); h3o.w = f2bf(a3.w);
            hp[0] = h0o; hp[1] = h1o; hp[2] = h2o; hp[3] = h3o;
        }
    }
}

extern "C" void kernel_launch(void* const* d_in, const int* in_sizes, int n_in,
                              void* d_out, int out_size, void* d_ws, size_t ws_size,
                              hipStream_t stream) {
    const float* nodes_in = (const float*)d_in[0];   // (B,N,H) f32
    const float* adj      = (const float*)d_in[1];   // (B,E,N) f32, binary
    const float* w1       = (const float*)d_in[2];   // (H+1)
    const float* w2       = (const float*)d_in[3];   // (H+1)

    char* ws = (char*)d_ws;
    size_t off = 0;
    u16* row_idx = (u16*)(ws + off); off += (size_t)B_ * E_ * CAP * sizeof(u16);
    u16* col_idx = (u16*)(ws + off); off += (size_t)B_ * N_ * CAP * sizeof(u16);
    int* row_cnt = (int*)(ws + off); off += (size_t)B_ * E_ * sizeof(int);
    int* col_cnt = (int*)(ws + off); off += (size_t)B_ * N_ * sizeof(int);
    int* cnt_chunk = (int*)(ws + off); off += (size_t)B_ * NC * N_ * sizeof(int);
    int* off_chunk = (int*)(ws + off); off += (size_t)B_ * NC * N_ * sizeof(int);
    u16* nodes_bf = (u16*)(ws + off); off += (size_t)B_ * N_ * H_ * sizeof(u16);
    u16* edge_bf  = (u16*)(ws + off); off += (size_t)B_ * E_ * H_ * sizeof(u16);
    u64* bits     = (u64*)(ws + off); off += (size_t)B_ * E_ * NW * sizeof(u64);

    float* out_nodes = (float*)d_out;                       // (B,N,H)
    float* out_edge  = out_nodes + (size_t)B_ * N_ * H_;    // (B,E,H)

    adj_to_bits   <<<dim3(B_ * E_), dim3(256), 0, stream>>>(adj, bits);
    rows_from_bits<<<dim3(B_ * E_ / 4), dim3(256), 0, stream>>>(bits, row_idx, row_cnt);
    col_count_bits<<<dim3(B_ * NC * 4), dim3(256), 0, stream>>>(bits, cnt_chunk);
    col_prefix    <<<dim3(B_ * N_ / 256), dim3(256), 0, stream>>>(cnt_chunk, off_chunk, col_cnt);
    col_place_bits<<<dim3(B_ * NC * 4), dim3(256), 0, stream>>>(bits, off_chunk, col_idx);
    to_bf16       <<<dim3(B_ * N_ * H_ / 1024), dim3(256), 0, stream>>>(nodes_in, nodes_bf);
    edge_init     <<<dim3(B_ * E_ / 4), dim3(256), 0, stream>>>(nodes_bf, row_idx, row_cnt, edge_bf);

    // s=0: intermediates -> bf16 shadows only (wfp=0)
    attn_gather<<<dim3(B_ * E_ / 4), dim3(256), 0, stream>>>(
        edge_bf, nodes_bf, w1, row_idx, row_cnt, out_edge, edge_bf, 1, 0);
    attn_gather<<<dim3(B_ * N_ / 4), dim3(256), 0, stream>>>(
        nodes_bf, edge_bf, w2, col_idx, col_cnt, out_nodes, nodes_bf, 1, 0);
    // s=1: finals -> fp32 outputs (wfp=1); edge also keeps bf16 for beta's kv
    attn_gather<<<dim3(B_ * E_ / 4), dim3(256), 0, stream>>>(
        edge_bf, nodes_bf, w1, row_idx, row_cnt, out_edge, edge_bf, 1, 1);
    attn_gather<<<dim3(B_ * N_ / 4), dim3(256), 0, stream>>>(
        nodes_bf, edge_bf, w2, col_idx, col_cnt, out_nodes, nodes_bf, 0, 1);
}